// Round 1
// baseline (74.122 us; speedup 1.0000x reference)
//
#include <hip/hip_runtime.h>

// InterDistanceLossV2: masked relative pairwise-distance loss.
// loss = sum_b sum_ij m_i m_j * |dp_ij - dt_ij| / (dt_ij + eps)  /  sum_b (sum_i m_i)^2
// Strategy: per-batch column compaction into LDS (only active points matter),
// deterministic row partition by original index (mod NCHUNKS), 4-row register
// blocking, wave-shuffle reduce + one float atomic per wave.

constexpr int   NTHREADS = 256;
constexpr int   NCHUNKS  = 32;   // row chunks per batch -> grid = B*32 = 1024 blocks
constexpr int   RBLK     = 4;    // rows register-blocked per inner pass
constexpr float EPS      = 1e-8f;

__global__ __launch_bounds__(NTHREADS) void idl_main(
    const float* __restrict__ preds, const float* __restrict__ targets,
    const int* __restrict__ mask, float* __restrict__ ws, int N)
{
    const int b     = blockIdx.x / NCHUNKS;
    const int chunk = blockIdx.x % NCHUNKS;

    // Compacted active-point coordinates (columns), SoA for conflict-free LDS.
    __shared__ float spx[1024], spy[1024], spz[1024];
    __shared__ float stx[1024], sty[1024], stz[1024];
    __shared__ int   s_rows[64];        // active original row indices of this chunk (<= N/NCHUNKS)
    __shared__ int   s_nrows, s_cnt;

    const float* pb = preds   + (size_t)b * N * 3;
    const float* tb = targets + (size_t)b * N * 3;
    const int*   mb = mask    + (size_t)b * N;

    if (threadIdx.x == 0) s_cnt = 0;
    __syncthreads();

    // Column compaction: order nondeterministic across blocks, but every active
    // column appears exactly once, so pair coverage is exact (only FP sum order varies).
    for (int j = threadIdx.x; j < N; j += NTHREADS) {
        if (mb[j] != 0) {
            int p = atomicAdd(&s_cnt, 1);
            spx[p] = pb[j * 3 + 0]; spy[p] = pb[j * 3 + 1]; spz[p] = pb[j * 3 + 2];
            stx[p] = tb[j * 3 + 0]; sty[p] = tb[j * 3 + 1]; stz[p] = tb[j * 3 + 2];
        }
    }
    // Deterministic row list: original indices i == chunk (mod NCHUNKS) with mask set.
    if (threadIdx.x == 0) {
        int nr = 0;
        for (int i = chunk; i < N; i += NCHUNKS)
            if (mb[i] != 0) s_rows[nr++] = i;
        s_nrows = nr;
    }
    __syncthreads();

    const int K     = s_cnt;
    const int nrows = s_nrows;

    float acc = 0.0f;
    for (int rg = 0; rg < nrows; rg += RBLK) {
        float rpx[RBLK], rpy[RBLK], rpz[RBLK];
        float rtx[RBLK], rty[RBLK], rtz[RBLK];
        bool  rv[RBLK];
#pragma unroll
        for (int k = 0; k < RBLK; ++k) {
            const int rr = rg + k;
            rv[k] = rr < nrows;
            const int i = rv[k] ? s_rows[rr] : 0;
            rpx[k] = rv[k] ? pb[i * 3 + 0] : 0.0f;
            rpy[k] = rv[k] ? pb[i * 3 + 1] : 0.0f;
            rpz[k] = rv[k] ? pb[i * 3 + 2] : 0.0f;
            rtx[k] = rv[k] ? tb[i * 3 + 0] : 0.0f;
            rty[k] = rv[k] ? tb[i * 3 + 1] : 0.0f;
            rtz[k] = rv[k] ? tb[i * 3 + 2] : 0.0f;
        }
        for (int j = threadIdx.x; j < K; j += NTHREADS) {
            const float jpx = spx[j], jpy = spy[j], jpz = spz[j];
            const float jtx = stx[j], jty = sty[j], jtz = stz[j];
#pragma unroll
            for (int k = 0; k < RBLK; ++k) {
                if (rv[k]) {   // wave-uniform branch
                    float dx = jpx - rpx[k], dy = jpy - rpy[k], dz = jpz - rpz[k];
                    float dp = sqrtf(dx * dx + dy * dy + dz * dz);
                    float ex = jtx - rtx[k], ey = jty - rty[k], ez = jtz - rtz[k];
                    float dt = sqrtf(ex * ex + ey * ey + ez * ez);
                    acc += fabsf(dp - dt) / (dt + EPS);
                }
            }
        }
    }

    // Wave64 shuffle reduce, then one global float atomic per wave.
    for (int off = 32; off > 0; off >>= 1)
        acc += __shfl_down(acc, off, 64);
    if ((threadIdx.x & 63) == 0)
        atomicAdd(&ws[0], acc);

    // Denominator: sum over batches of K^2, added once per batch (chunk 0).
    if (chunk == 0 && threadIdx.x == 0)
        atomicAdd(&ws[1], (float)K * (float)K);
}

__global__ void idl_final(const float* __restrict__ ws, float* __restrict__ out)
{
    out[0] = ws[0] / ws[1];
}

extern "C" void kernel_launch(void* const* d_in, const int* in_sizes, int n_in,
                              void* d_out, int out_size, void* d_ws, size_t ws_size,
                              hipStream_t stream)
{
    const float* preds   = (const float*)d_in[0];
    const float* targets = (const float*)d_in[1];
    const int*   mask    = (const int*)d_in[2];
    float* ws = (float*)d_ws;

    const int N = 1024;                 // fixed by setup_inputs (B=32, N=1024, D=3)
    const int B = in_sizes[2] / N;

    // d_ws is poisoned (0xAA) once and never re-poisoned between replays:
    // zero the two accumulators every call (graph-capture safe).
    hipMemsetAsync(ws, 0, 2 * sizeof(float), stream);

    idl_main<<<dim3(B * NCHUNKS), NTHREADS, 0, stream>>>(preds, targets, mask, ws, N);
    idl_final<<<1, 1, 0, stream>>>(ws, (float*)d_out);
}

// Round 2
// 20.009 us; speedup vs baseline: 3.7045x; 3.7045x over previous
//
#include <hip/hip_runtime.h>

// InterDistanceLossV2: masked relative pairwise-distance loss.
// loss = sum_b sum_ij m_i m_j |dp_ij - dt_ij| / (dt_ij + eps)  /  sum_b K_b^2
//
// R2 design: grid = B * 32 rowchunks * 2 colhalves = 2048 blocks (8/CU = 100% occ,
// LDS 12.3KB). Parallel ballot row-list, LDS column compaction per half,
// fast sqrt/rcp, no atomics (per-block partials + final reduce kernel).

constexpr int   NT    = 256;
constexpr int   ROWCH = 32;            // row chunks per batch (32 rows each)
constexpr int   SUBS  = ROWCH * 2;     // x2 column halves -> 64 blocks per batch
constexpr int   RBLK  = 4;
constexpr float EPS   = 1e-8f;

__global__ __launch_bounds__(NT) void idl_main(
    const float* __restrict__ preds, const float* __restrict__ targets,
    const int* __restrict__ mask, float* __restrict__ partials,
    float* __restrict__ counts, int N)
{
    const int bid      = blockIdx.x;
    const int b        = bid / SUBS;
    const int sub      = bid % SUBS;
    const int rowBase  = (sub >> 1) * 32;
    const int colBase  = (sub & 1) * 512;

    __shared__ float scpx[512], scpy[512], scpz[512];
    __shared__ float sctx[512], scty[512], sctz[512];
    __shared__ int   s_rows[32];
    __shared__ int   s_nrows, s_cnt;
    __shared__ float s_red[NT / 64];

    const float* pb = preds   + (size_t)b * N * 3;
    const float* tb = targets + (size_t)b * N * 3;
    const int*   mb = mask    + (size_t)b * N;
    const int    tid = threadIdx.x;

    if (tid == 0) s_cnt = 0;
    __syncthreads();

    // Column compaction of this half (order nondeterministic -> only FP sum order varies).
    for (int j = colBase + tid; j < colBase + 512; j += NT) {
        if (mb[j] != 0) {
            int p = atomicAdd(&s_cnt, 1);
            scpx[p] = pb[j * 3 + 0]; scpy[p] = pb[j * 3 + 1]; scpz[p] = pb[j * 3 + 2];
            sctx[p] = tb[j * 3 + 0]; scty[p] = tb[j * 3 + 1]; sctz[p] = tb[j * 3 + 2];
        }
    }
    // Row list: wave 0, ballot + popcount (deterministic, ordered).
    if (tid < 64) {
        bool act = (tid < 32) && (mb[rowBase + tid] != 0);
        unsigned long long bal = __ballot(act);
        if (act) {
            int pos = __popcll(bal & ((1ull << tid) - 1ull));
            s_rows[pos] = rowBase + tid;
        }
        if (tid == 0) s_nrows = (int)__popcll(bal);
    }
    __syncthreads();

    const int Kc    = s_cnt;
    const int nrows = s_nrows;

    float acc = 0.0f;
    for (int rg = 0; rg < nrows; rg += RBLK) {
        float rpx[RBLK], rpy[RBLK], rpz[RBLK];
        float rtx[RBLK], rty[RBLK], rtz[RBLK];
        bool  rv[RBLK];
#pragma unroll
        for (int k = 0; k < RBLK; ++k) {
            const int rr = rg + k;
            rv[k] = rr < nrows;
            const int i = rv[k] ? s_rows[rr] : s_rows[0];   // nrows>=1 here
            rpx[k] = pb[i * 3 + 0]; rpy[k] = pb[i * 3 + 1]; rpz[k] = pb[i * 3 + 2];
            rtx[k] = tb[i * 3 + 0]; rty[k] = tb[i * 3 + 1]; rtz[k] = tb[i * 3 + 2];
        }
        for (int j = tid; j < Kc; j += NT) {
            const float jpx = scpx[j], jpy = scpy[j], jpz = scpz[j];
            const float jtx = sctx[j], jty = scty[j], jtz = sctz[j];
#pragma unroll
            for (int k = 0; k < RBLK; ++k) {
                if (rv[k]) {   // block-uniform predicate
                    float dx = jpx - rpx[k], dy = jpy - rpy[k], dz = jpz - rpz[k];
                    float sp = fmaf(dx, dx, fmaf(dy, dy, dz * dz));
                    float dp = __builtin_amdgcn_sqrtf(sp);
                    float ex = jtx - rtx[k], ey = jty - rty[k], ez = jtz - rtz[k];
                    float st = fmaf(ex, ex, fmaf(ey, ey, ez * ez));
                    float dt = __builtin_amdgcn_sqrtf(st);
                    acc = fmaf(fabsf(dp - dt), __builtin_amdgcn_rcpf(dt + EPS), acc);
                }
            }
        }
    }

    // Block reduction -> one partial per block (no atomics).
    for (int off = 32; off > 0; off >>= 1)
        acc += __shfl_down(acc, off, 64);
    if ((tid & 63) == 0) s_red[tid >> 6] = acc;
    __syncthreads();
    if (tid == 0) {
        float s = 0.0f;
#pragma unroll
        for (int w = 0; w < NT / 64; ++w) s += s_red[w];
        partials[bid] = s;
    }

    // Designated block per batch writes K_b (full-batch mask count).
    if (sub == 0) {
        __shared__ int s_ri[NT / 64];
        int c = 0;
        for (int i = tid; i < N; i += NT) c += (mb[i] != 0);
        for (int off = 32; off > 0; off >>= 1)
            c += __shfl_down(c, off, 64);
        if ((tid & 63) == 0) s_ri[tid >> 6] = c;
        __syncthreads();
        if (tid == 0) {
            int t = 0;
#pragma unroll
            for (int w = 0; w < NT / 64; ++w) t += s_ri[w];
            counts[b] = (float)t;
        }
    }
}

__global__ __launch_bounds__(256) void idl_final(
    const float* __restrict__ partials, int nP,
    const float* __restrict__ counts, int B, float* __restrict__ out)
{
    __shared__ float s_n[4], s_d[4];
    const int tid = threadIdx.x;
    float num = 0.0f, den = 0.0f;
    for (int i = tid; i < nP; i += 256) num += partials[i];
    for (int i = tid; i < B;  i += 256) { float c = counts[i]; den = fmaf(c, c, den); }
    for (int off = 32; off > 0; off >>= 1) {
        num += __shfl_down(num, off, 64);
        den += __shfl_down(den, off, 64);
    }
    if ((tid & 63) == 0) { s_n[tid >> 6] = num; s_d[tid >> 6] = den; }
    __syncthreads();
    if (tid == 0) {
        float n = 0.0f, d = 0.0f;
#pragma unroll
        for (int w = 0; w < 4; ++w) { n += s_n[w]; d += s_d[w]; }
        out[0] = n / d;
    }
}

// ---------- fallback (round-1 style, needs only 8B of ws) ----------
__global__ __launch_bounds__(NT) void idl_fb(
    const float* __restrict__ preds, const float* __restrict__ targets,
    const int* __restrict__ mask, float* __restrict__ ws, int N)
{
    const int b     = blockIdx.x / 32;
    const int chunk = blockIdx.x % 32;
    __shared__ float spx[1024], spy[1024], spz[1024];
    __shared__ float stx[1024], sty[1024], stz[1024];
    __shared__ int   s_rows[32];
    __shared__ int   s_nrows, s_cnt;
    const float* pb = preds   + (size_t)b * N * 3;
    const float* tb = targets + (size_t)b * N * 3;
    const int*   mb = mask    + (size_t)b * N;
    const int tid = threadIdx.x;
    if (tid == 0) s_cnt = 0;
    __syncthreads();
    for (int j = tid; j < N; j += NT) {
        if (mb[j] != 0) {
            int p = atomicAdd(&s_cnt, 1);
            spx[p] = pb[j*3+0]; spy[p] = pb[j*3+1]; spz[p] = pb[j*3+2];
            stx[p] = tb[j*3+0]; sty[p] = tb[j*3+1]; stz[p] = tb[j*3+2];
        }
    }
    if (tid < 64) {
        bool act = (tid < 32) && (mb[chunk * 32 + tid] != 0);
        unsigned long long bal = __ballot(act);
        if (act) s_rows[__popcll(bal & ((1ull << tid) - 1ull))] = chunk * 32 + tid;
        if (tid == 0) s_nrows = (int)__popcll(bal);
    }
    __syncthreads();
    const int K = s_cnt, nrows = s_nrows;
    float acc = 0.0f;
    for (int rg = 0; rg < nrows; ++rg) {
        const int i = s_rows[rg];
        float rpx = pb[i*3+0], rpy = pb[i*3+1], rpz = pb[i*3+2];
        float rtx = tb[i*3+0], rty = tb[i*3+1], rtz = tb[i*3+2];
        for (int j = tid; j < K; j += NT) {
            float dx = spx[j]-rpx, dy = spy[j]-rpy, dz = spz[j]-rpz;
            float dp = __builtin_amdgcn_sqrtf(fmaf(dx,dx,fmaf(dy,dy,dz*dz)));
            float ex = stx[j]-rtx, ey = sty[j]-rty, ez = stz[j]-rtz;
            float dt = __builtin_amdgcn_sqrtf(fmaf(ex,ex,fmaf(ey,ey,ez*ez)));
            acc = fmaf(fabsf(dp-dt), __builtin_amdgcn_rcpf(dt + EPS), acc);
        }
    }
    for (int off = 32; off > 0; off >>= 1) acc += __shfl_down(acc, off, 64);
    if ((tid & 63) == 0) atomicAdd(&ws[0], acc);
    if (chunk == 0 && tid == 0) atomicAdd(&ws[1], (float)K * (float)K);
}
__global__ void idl_fb_final(const float* __restrict__ ws, float* __restrict__ out)
{ out[0] = ws[0] / ws[1]; }

extern "C" void kernel_launch(void* const* d_in, const int* in_sizes, int n_in,
                              void* d_out, int out_size, void* d_ws, size_t ws_size,
                              hipStream_t stream)
{
    const float* preds   = (const float*)d_in[0];
    const float* targets = (const float*)d_in[1];
    const int*   mask    = (const int*)d_in[2];
    const int N = 1024;                     // fixed by setup_inputs
    const int B = in_sizes[2] / N;
    const int nBlocks = B * SUBS;
    const size_t need = (size_t)(nBlocks + B) * sizeof(float);

    if (ws_size >= need) {
        float* partials = (float*)d_ws;
        float* counts   = partials + nBlocks;
        idl_main<<<dim3(nBlocks), NT, 0, stream>>>(preds, targets, mask, partials, counts, N);
        idl_final<<<dim3(1), 256, 0, stream>>>(partials, nBlocks, counts, B, (float*)d_out);
    } else {
        float* ws = (float*)d_ws;
        hipMemsetAsync(ws, 0, 2 * sizeof(float), stream);
        idl_fb<<<dim3(B * 32), NT, 0, stream>>>(preds, targets, mask, ws, N);
        idl_fb_final<<<dim3(1), 1, 0, stream>>>(ws, (float*)d_out);
    }
}